// Round 8
// baseline (195.044 us; speedup 1.0000x reference)
//
#include <hip/hip_runtime.h>
#include <hip/hip_bf16.h>

#define SEQ 2048
#define DMODEL 1024
#define NHEAD 16
#define HDIM 64
#define DPOS 64
#define BATCH 2

constexpr float EVENT_HORIZON = 1e-6f;
constexpr float MAX_FORCE = 50.0f;
constexpr float CURV = 0.15f;
constexpr float LOG2E = 1.44269504f;
// P = exp2(min(f,50)*log2e - S2), S2 = 39*log2e: e <= 2^15.87 = 59847 (fp16-safe),
// ratio-invariant under softmax normalization.
constexpr float SHIFT = 39.0f;

typedef __attribute__((ext_vector_type(8))) short frag8;        // 8 bf16/ushort
typedef __attribute__((ext_vector_type(4))) unsigned int uint4v;
typedef __attribute__((ext_vector_type(8))) _Float16 half8;     // 8 fp16
typedef __attribute__((ext_vector_type(2))) _Float16 half2t;    // 2 fp16
typedef __attribute__((ext_vector_type(4))) float frag4f;       // 4 fp32 (C/D)

union A8u { half8 v; half2t h[4]; };

__device__ inline short bfbits(float f) {
  __hip_bfloat16 h = __float2bfloat16(f);
  return *reinterpret_cast<short*>(&h);
}
__device__ inline float fbits(unsigned u) {
  union { unsigned u; float f; } c; c.u = u; return c.f;
}
__device__ inline half2t pkrtz(float a, float b) {
  return __builtin_bit_cast(half2t, __builtin_amdgcn_cvt_pkrtz(a, b));
}
// native 2^x, single v_exp_f32 (no hidden *log2e mul like __expf)
__device__ inline float exp2_fast(float x) {
  float r;
  asm("v_exp_f32 %0, %1" : "=v"(r) : "v"(x));
  return r;
}
// XOR swizzle in 16B units: row = 8 units (128B); b128 frag reads (fixed unit,
// 16 consecutive rows) and staging writes both cover banks <=2-way (free).
__device__ inline int swz(int row, int u) { return row * 8 + (u ^ (row & 7)); }

// ---------------------------------------------------------------------------
// Fused prep (role A, 2048 blocks) + invdist (role B, 1024 blocks).
// Role A: transpose x -> xt[bh][d][j] fp16 AND masses = softplus(x . Wm).
// Role B: LDS-tiled pairwise distance -> invd bf16.
// ---------------------------------------------------------------------------
__global__ __launch_bounds__(256) void prep_and_dist(
    const float* __restrict__ x, const float* __restrict__ Wm,
    const float* __restrict__ pos,
    _Float16* __restrict__ xt, float* __restrict__ masses,
    unsigned short* __restrict__ invd) {
  __shared__ float Li[64 * 68];
  __shared__ float Lj[64 * 68];
  int bid = blockIdx.x;
  int t = threadIdx.x;

  if (bid < 2048) {
    // ---- role A: prep_xt_masses ----
    int bh = bid & 31;
    int h = bh & 15, b = bh >> 4;
    int d = t & 63;
    int jg = (t >> 6) + ((bid >> 5) << 2);   // j-group of 8, 0..255
    int j0 = jg * 8;
    const float* src = x + (size_t)(b * SEQ) * DMODEL + h * HDIM + d;
    float wmd = Wm[h * HDIM + d];
    half8 v;
    float fv[8];
#pragma unroll
    for (int jj = 0; jj < 8; ++jj) {
      float f = src[(size_t)(j0 + jj) * DMODEL];
      fv[jj] = f;
      v[jj] = (_Float16)f;
    }
    *(half8*)(xt + ((size_t)bh * HDIM + d) * SEQ + j0) = v;

    float msum = 0.f;
#pragma unroll
    for (int jj = 0; jj < 8; ++jj) {
      float s = fv[jj] * wmd;
#pragma unroll
      for (int off = 32; off; off >>= 1) s += __shfl_xor(s, off, 64);
      if (d == jj) msum = s;      // lane jj keeps row j0+jj's dot
    }
    if (d < 8) {
      float m = (msum > 20.f) ? msum : log1pf(expf(msum));
      masses[(size_t)bh * SEQ + j0 + d] = m;
    }
    return;
  }

  // ---- role B: invdist ----
  int ib = bid - 2048;
  int i0 = (ib >> 5) * 64, j0 = (ib & 31) * 64;

  int kk = (t & 15) * 4;
  int rr = t >> 4;
#pragma unroll
  for (int q = 0; q < 4; ++q) {
    int row = q * 16 + rr;
    float4 a = *(const float4*)(pos + (size_t)(i0 + row) * DPOS + kk);
    float4 b = *(const float4*)(pos + (size_t)(j0 + row) * DPOS + kk);
    Li[(kk + 0) * 68 + row] = a.x; Li[(kk + 1) * 68 + row] = a.y;
    Li[(kk + 2) * 68 + row] = a.z; Li[(kk + 3) * 68 + row] = a.w;
    Lj[(kk + 0) * 68 + row] = b.x; Lj[(kk + 1) * 68 + row] = b.y;
    Lj[(kk + 2) * 68 + row] = b.z; Lj[(kk + 3) * 68 + row] = b.w;
  }
  __syncthreads();

  int ti = (t >> 4) * 4;
  int tj = (t & 15) * 4;

  float acc[4][4];
#pragma unroll
  for (int a = 0; a < 4; ++a)
#pragma unroll
    for (int b = 0; b < 4; ++b) acc[a][b] = 0.f;

#pragma unroll 8
  for (int k = 0; k < 64; ++k) {
    float4 a = *(const float4*)(&Li[k * 68 + ti]);
    float4 b = *(const float4*)(&Lj[k * 68 + tj]);
    float av[4] = {a.x, a.y, a.z, a.w};
    float bv[4] = {b.x, b.y, b.z, b.w};
#pragma unroll
    for (int mi = 0; mi < 4; ++mi)
#pragma unroll
      for (int mj = 0; mj < 4; ++mj) {
        float d = av[mi] - bv[mj];
        acc[mi][mj] += d * d;
      }
  }

#pragma unroll
  for (int mi = 0; mi < 4; ++mi) {
    ushort4 o;
    unsigned short* op = (unsigned short*)&o;
#pragma unroll
    for (int mj = 0; mj < 4; ++mj) {
      float d2 = acc[mi][mj];
      float dn = sqrtf(d2 + EVENT_HORIZON);
      float w = d2 * (1.f + CURV * __cosf(dn));
      op[mj] = (unsigned short)bfbits(1.0f / fmaxf(w, EVENT_HORIZON));
    }
    *(ushort4*)(&invd[(size_t)(i0 + ti + mi) * SEQ + j0 + tj]) = o;
  }
}

// ---------------------------------------------------------------------------
// Kernel 3: fused gravitational attention, fp16 MFMA PV.
// r8 = r7 (block-level j-split, 8 blocks/CU) + NaN guard: the j-half
// without the diagonal can have ALL fp16 P values underflow to 0 ->
// accs==0 -> 1/0*0 = NaN. Guard: s = accs>0 ? 1/accs : 0 (exact: zero
// partial gets zero combine weight; the diagonal half always has
// accs >= 2^15.87 so s0+s1 > 0).
// ---------------------------------------------------------------------------
__global__ __launch_bounds__(256, 8) void attn_mfma_kernel(
    const _Float16* __restrict__ xt, const float* __restrict__ masses,
    const unsigned short* __restrict__ invd, const float* __restrict__ G,
    _Float16* __restrict__ A0, _Float16* __restrict__ A1,
    float* __restrict__ sums0, float* __restrict__ sums1) {
  __shared__ _Float16 Vs[2][64 * 64];   // [buf], 8 KB each, XOR-swizzled
  __shared__ float Ms[2][64];           // masses chunk broadcast

  constexpr float S2 = SHIFT * LOG2E;                 // 56.265
  constexpr float C2 = (MAX_FORCE - SHIFT) * LOG2E;   // 15.870

  int bid = blockIdx.x;
  // XCD-clustered bijective decode: x in [0,8) = XCD slot.
  int xs = bid & 7, y = bid >> 3;            // y in [0,256)
  int bh = xs * 4 + (y & 3);                 // 4 bh per XCD
  int rest = y >> 2;                         // [0,64)
  int jh = rest & 1;
  int iblk = rest >> 1;                      // [0,32)
  int h = bh & (NHEAD - 1), b = bh >> 4;
  int i0 = iblk * 64;
  int jbase = jh * 1024;
  int t = threadIdx.x, w = t >> 6, lane = t & 63;
  int l15 = lane & 15, quad = lane >> 4;
  int iw = i0 + w * 16;

  float gabs = fabsf(G[h]);
  const float* mrow = masses + (size_t)bh * SEQ;
  float cm = gabs * mrow[iw + l15] * LOG2E;           // row scalar, log2 domain
  const unsigned short* ivrow = invd + (size_t)(iw + l15) * SEQ + jbase;

  // staging role: thread t -> d-row t>>2, 16B-units {2*(t&3), 2*(t&3)+1}
  int srow = t >> 2, sunit = (t & 3) * 2;
  const _Float16* srcrow =
      xt + ((size_t)bh * HDIM + srow) * SEQ + jbase + sunit * 8;
  int swzoff0 = swz(srow, sunit) * 8;
  int swzoff1 = swz(srow, sunit + 1) * 8;

  half8 vone;
#pragma unroll
  for (int k = 0; k < 8; ++k) vone[k] = (_Float16)1.f;

  frag4f acc[4];
#pragma unroll
  for (int nt = 0; nt < 4; ++nt) acc[nt] = (frag4f)0.f;
  frag4f accs = (frag4f)0.f;          // partial row sums

  // ---- prologue: chunk 0 ----
  *(half8*)(&Vs[0][0] + swzoff0) = *(const half8*)(srcrow);
  *(half8*)(&Vs[0][0] + swzoff1) = *(const half8*)(srcrow + 8);
  if (t < 64) Ms[0][t] = mrow[jbase + t];
  frag8 iv_cur[2], iv_nxt[2];
  iv_cur[0] = *(const frag8*)(ivrow + quad * 8);
  iv_cur[1] = *(const frag8*)(ivrow + 32 + quad * 8);
  __syncthreads();

  for (int cc = 0; cc < 8; ++cc) {
#pragma unroll
    for (int u = 0; u < 2; ++u) {
      int c = cc * 2 + u;               // buf index u is compile-time
      // ---- issue prefetches for chunk c+1 (latency hidden by compute) ----
      half8 vpre0, vpre1;
      float mload = 0.f;
      if (c < 15) {
        int jn = (c + 1) * 64;
        vpre0 = *(const half8*)(srcrow + jn);
        vpre1 = *(const half8*)(srcrow + jn + 8);
        if (t < 64) mload = mrow[jbase + jn + t];
        iv_nxt[0] = *(const frag8*)(ivrow + jn + quad * 8);
        iv_nxt[1] = *(const frag8*)(ivrow + jn + 32 + quad * 8);
      }

      // ---- compute chunk c from buf[u] ----
      const _Float16* Vbase = &Vs[u][0];
      const float* Mbase = &Ms[u][0];

#pragma unroll
      for (int kh = 0; kh < 2; ++kh) {
        // masses broadcast from LDS (same addr across l15 -> bank broadcast)
        const float* mp = Mbase + kh * 32 + quad * 8;
        float4 mjl = *(const float4*)(mp);
        float4 mjh = *(const float4*)(mp + 4);
        float mjf[8] = {mjl.x, mjl.y, mjl.z, mjl.w,
                        mjh.x, mjh.y, mjh.z, mjh.w};
        uint4v uv = __builtin_bit_cast(uint4v, iv_cur[kh]);
        float e[8];
#pragma unroll
        for (int p = 0; p < 4; ++p) {
          float ivA = fbits(uv[p] << 16);          // even j: low bf16
          float ivB = fbits(uv[p] & 0xffff0000u);  // odd j: high bf16
          float fA = fmaf(cm * mjf[2 * p], ivA, -S2);
          float fB = fmaf(cm * mjf[2 * p + 1], ivB, -S2);
          e[2 * p] = exp2_fast(fminf(fA, C2));
          e[2 * p + 1] = exp2_fast(fminf(fB, C2));
        }
        A8u A;
#pragma unroll
        for (int p = 0; p < 4; ++p)
          A.h[p] = pkrtz(e[2 * p], e[2 * p + 1]);

        __builtin_amdgcn_s_setprio(1);
        accs = __builtin_amdgcn_mfma_f32_16x16x32_f16(A.v, vone, accs, 0, 0, 0);
#pragma unroll
        for (int nt = 0; nt < 4; ++nt) {
          half8 Bf = *(const half8*)(Vbase + swz(nt * 16 + l15, kh * 4 + quad) * 8);
          acc[nt] = __builtin_amdgcn_mfma_f32_16x16x32_f16(A.v, Bf, acc[nt], 0, 0, 0);
        }
        __builtin_amdgcn_s_setprio(0);
      }

      // ---- rotate prefetches in; write V/M prefetch to other buffer ----
      if (c < 15) {
        _Float16* Vn = &Vs[u ^ 1][0];
        *(half8*)(Vn + swzoff0) = vpre0;
        *(half8*)(Vn + swzoff1) = vpre1;
        if (t < 64) Ms[u ^ 1][t] = mload;
        iv_cur[0] = iv_nxt[0]; iv_cur[1] = iv_nxt[1];
      }
      __syncthreads();
    }
  }

  // ---- self-normalize partial + store fp16 tile and partial row sums.
  // accs==0 (all-underflow half) -> partial is exactly 0; store s=0 so the
  // combine weight is 0 for this half. ----
  _Float16* Aout = jh ? A1 : A0;
  float* sout = jh ? sums1 : sums0;
#pragma unroll
  for (int reg = 0; reg < 4; ++reg) {
    int r = quad * 4 + reg;            // C/D row within 16x16 tile
    size_t m = (size_t)(b * SEQ + iw + r);
    float s = (accs[reg] > 0.f) ? (1.f / accs[reg]) : 0.f;
#pragma unroll
    for (int nt = 0; nt < 4; ++nt) {
      Aout[m * DMODEL + h * HDIM + nt * 16 + l15] =
          (_Float16)(acc[nt][reg] * s);
    }
    if (l15 == 0) sout[m * NHEAD + h] = accs[reg];
  }
}

// ---------------------------------------------------------------------------
// Kernel 4: out = combine(A0,A1) @ Wout^T via fp16 MFMA. A-staging combines
// the two j-half partials: A = w0*A0 + w1*A1, w0 = s0/(s0+s1), via packed
// fp16 fma (BK=64 == head dim -> one weight scalar per (row, kc)). Wout
// f32->fp16 on the fly in B-staging. 128x64 tile, double-buffered swizzled
// LDS. grid (16,32) = 512 blocks.
// ---------------------------------------------------------------------------
__global__ __launch_bounds__(256) void out_gemm_mfma(
    const _Float16* __restrict__ A0, const _Float16* __restrict__ A1,
    const float* __restrict__ sums0, const float* __restrict__ sums1,
    const float* __restrict__ Wout, float* __restrict__ C) {
  __shared__ _Float16 As[2][128 * 64];   // 16 KB each
  __shared__ _Float16 Bs[2][64 * 64];    // 8 KB each

  int t = threadIdx.x, w = t >> 6, lane = t & 63;
  int l15 = lane & 15, quad = lane >> 4;
  int m0 = blockIdx.y * 128, n0 = blockIdx.x * 64;
  int mh = (w & 1) * 64, nh = (w >> 1) * 32;

  int ar = t >> 1;  int aku = (t & 1) * 4;
  int br = t >> 2;  int bku = (t & 3) * 2;
  const _Float16* a0base = A0 + (size_t)(m0 + ar) * DMODEL + aku * 8;
  const _Float16* a1base = A1 + (size_t)(m0 + ar) * DMODEL + aku * 8;
  const float* s0p = sums0 + (size_t)(m0 + ar) * NHEAD;
  const float* s1p = sums1 + (size_t)(m0 + ar) * NHEAD;
  const float*    wbase = Wout + (size_t)(n0 + br) * DMODEL + bku * 8;

  frag4f acc[4][2];
#pragma unroll
  for (int mt = 0; mt < 4; ++mt)
#pragma unroll
    for (int nt = 0; nt < 2; ++nt) acc[mt][nt] = (frag4f)0.f;

  A8u a0q[4], a1q[4];
  half8 b0, b1;
  float s0, s1;

  // combine helper runs at staging-write time
  auto stage = [&](int buf) {
    float w0f = s0 / (s0 + s1);
    _Float16 w0 = (_Float16)w0f;
    _Float16 w1 = (_Float16)(1.f - w0f);
    half2t w0h = {w0, w0}, w1h = {w1, w1};
    _Float16* aw = As[buf]; _Float16* bw = Bs[buf];
#pragma unroll
    for (int q = 0; q < 4; ++q) {
      A8u o;
#pragma unroll
      for (int p = 0; p < 4; ++p)
        o.h[p] = a0q[q].h[p] * w0h + a1q[q].h[p] * w1h;   // v_pk_fma_f16
      *(half8*)(aw + swz(ar, aku + q) * 8) = o.v;
    }
    *(half8*)(bw + swz(br, bku + 0) * 8) = b0;
    *(half8*)(bw + swz(br, bku + 1) * 8) = b1;
  };
  auto loadk = [&](int kc) {
    const _Float16* ap0 = a0base + kc * 64;
    const _Float16* ap1 = a1base + kc * 64;
#pragma unroll
    for (int q = 0; q < 4; ++q) {
      a0q[q].v = *(const half8*)(ap0 + q * 8);
      a1q[q].v = *(const half8*)(ap1 + q * 8);
    }
    s0 = s0p[kc]; s1 = s1p[kc];
    const float* wp = wbase + kc * 64;
    float4 w0 = *(const float4*)(wp);      float4 w1 = *(const float4*)(wp + 4);
    float4 w2 = *(const float4*)(wp + 8);  float4 w3 = *(const float4*)(wp + 12);
    b0[0] = (_Float16)w0.x; b0[1] = (_Float16)w0.y; b0[2] = (_Float16)w0.z; b0[3] = (_Float16)w0.w;
    b0[4] = (_Float16)w1.x; b0[5] = (_Float16)w1.y; b0[6] = (_Float16)w1.z; b0[7] = (_Float16)w1.w;
    b1[0] = (_Float16)w2.x; b1[1] = (_Float16)w2.y; b1[2] = (_Float16)w2.z; b1[3] = (_Float16)w2.w;
    b1[4] = (_Float16)w3.x; b1[5] = (_Float16)w3.y; b1[6] = (_Float16)w3.z; b1[7] = (_Float16)w3.w;
  };

  loadk(0);
  stage(0);
  __syncthreads();

  for (int kk = 0; kk < 8; ++kk) {
#pragma unroll
    for (int u = 0; u < 2; ++u) {
      int kc = kk * 2 + u;              // buf index u is compile-time
      if (kc < 15) loadk(kc + 1);

      const _Float16* ac = As[u];
      const _Float16* bc = Bs[u];
#pragma unroll
      for (int kh = 0; kh < 2; ++kh) {
        half8 Af[4], Bf[2];
#pragma unroll
        for (int mt = 0; mt < 4; ++mt)
          Af[mt] = *(const half8*)(ac + swz(mh + mt * 16 + l15, kh * 4 + quad) * 8);
#pragma unroll
        for (int nt = 0; nt < 2; ++nt)
          Bf[nt] = *(const half8*)(bc + swz(nh + nt * 16 + l15, kh * 4 + quad) * 8);
        __builtin_amdgcn_s_setprio(1);
#pragma unroll
        for (int mt = 0; mt < 4; ++mt)
#pragma unroll
          for (int nt = 0; nt < 2; ++nt)
            acc[mt][nt] = __builtin_amdgcn_mfma_f32_16x16x32_f16(Af[mt], Bf[nt], acc[mt][nt], 0, 0, 0);
        __builtin_amdgcn_s_setprio(0);
      }

      if (kc < 15) stage(u ^ 1);
      __syncthreads();
    }
  }

#pragma unroll
  for (int mt = 0; mt < 4; ++mt)
#pragma unroll
    for (int nt = 0; nt < 2; ++nt)
#pragma unroll
      for (int reg = 0; reg < 4; ++reg) {
        int m = m0 + mh + mt * 16 + quad * 4 + reg;
        int n = n0 + nh + nt * 16 + l15;
        C[(size_t)m * DMODEL + n] = acc[mt][nt][reg];
      }
}

// ---------------------------------------------------------------------------
extern "C" void kernel_launch(void* const* d_in, const int* in_sizes, int n_in,
                              void* d_out, int out_size, void* d_ws, size_t ws_size,
                              hipStream_t stream) {
  const float* x    = (const float*)d_in[0];
  const float* pos  = (const float*)d_in[1];
  const float* Wm   = (const float*)d_in[2];
  const float* G    = (const float*)d_in[3];
  const float* Wout = (const float*)d_in[4];
  float* out = (float*)d_out;

  char* wsb = (char*)d_ws;
  float* masses = (float*)wsb;                                      // 256 KB
  unsigned short* invd = (unsigned short*)(wsb + (1 << 18));        // 8 MB
  _Float16* A0 = (_Float16*)(wsb + (1 << 18) + (8 << 20));          // 8 MB
  _Float16* A1 = (_Float16*)(wsb + (1 << 18) + (16 << 20));         // 8 MB
  _Float16* xt = (_Float16*)(wsb + (1 << 18) + (24 << 20));         // 8 MB
  float* sums0 = (float*)(wsb + (1 << 18) + (32 << 20));            // 256 KB
  float* sums1 = (float*)(wsb + (1 << 18) + (32 << 20) + (1 << 18));// 256 KB

  prep_and_dist<<<dim3(3072), 256, 0, stream>>>(x, Wm, pos, xt, masses, invd);
  attn_mfma_kernel<<<dim3(2048), 256, 0, stream>>>(
      xt, masses, invd, G, A0, A1, sums0, sums1);
  out_gemm_mfma<<<dim3(DMODEL / 64, (BATCH * SEQ) / 128), 256, 0, stream>>>(
      A0, A1, sums0, sums1, Wout, out);
}

// Round 9
// 171.216 us; speedup vs baseline: 1.1392x; 1.1392x over previous
//
#include <hip/hip_runtime.h>
#include <hip/hip_bf16.h>

#define SEQ 2048
#define DMODEL 1024
#define NHEAD 16
#define HDIM 64
#define DPOS 64
#define BATCH 2

constexpr float EVENT_HORIZON = 1e-6f;
constexpr float MAX_FORCE = 50.0f;
constexpr float CURV = 0.15f;
constexpr float LOG2E = 1.44269504f;
// P = exp2(min(f,50)*log2e - S2), S2 = 39*log2e: e <= 2^15.87 = 59847 (fp16-safe),
// ratio-invariant under softmax normalization.
constexpr float SHIFT = 39.0f;

typedef __attribute__((ext_vector_type(8))) short frag8;        // 8 bf16/ushort
typedef __attribute__((ext_vector_type(4))) unsigned int uint4v;
typedef __attribute__((ext_vector_type(8))) _Float16 half8;     // 8 fp16
typedef __attribute__((ext_vector_type(2))) _Float16 half2t;    // 2 fp16
typedef __attribute__((ext_vector_type(4))) float frag4f;       // 4 fp32 (C/D)

union A8u { half8 v; half2t h[4]; };

__device__ inline short bfbits(float f) {
  __hip_bfloat16 h = __float2bfloat16(f);
  return *reinterpret_cast<short*>(&h);
}
__device__ inline float fbits(unsigned u) {
  union { unsigned u; float f; } c; c.u = u; return c.f;
}
__device__ inline half2t pkrtz(float a, float b) {
  return __builtin_bit_cast(half2t, __builtin_amdgcn_cvt_pkrtz(a, b));
}
// native 2^x, single v_exp_f32 (no hidden *log2e mul like __expf)
__device__ inline float exp2_fast(float x) {
  float r;
  asm("v_exp_f32 %0, %1" : "=v"(r) : "v"(x));
  return r;
}
// XOR swizzle in 16B units: row = 8 units (128B); b128 frag reads (fixed unit,
// 16 consecutive rows) and staging writes both cover banks <=2-way (free).
__device__ inline int swz(int row, int u) { return row * 8 + (u ^ (row & 7)); }

// ---------------------------------------------------------------------------
// Fused prep (role A, 2048 blocks) + invdist (role B, 1024 blocks).
// Role A: transpose x -> xt[bh][d][j] fp16 AND masses = softplus(x . Wm).
// Role B: LDS-tiled pairwise distance -> invd bf16.
// ---------------------------------------------------------------------------
__global__ __launch_bounds__(256) void prep_and_dist(
    const float* __restrict__ x, const float* __restrict__ Wm,
    const float* __restrict__ pos,
    _Float16* __restrict__ xt, float* __restrict__ masses,
    unsigned short* __restrict__ invd) {
  __shared__ float Li[64 * 68];
  __shared__ float Lj[64 * 68];
  int bid = blockIdx.x;
  int t = threadIdx.x;

  if (bid < 2048) {
    // ---- role A: prep_xt_masses ----
    int bh = bid & 31;
    int h = bh & 15, b = bh >> 4;
    int d = t & 63;
    int jg = (t >> 6) + ((bid >> 5) << 2);   // j-group of 8, 0..255
    int j0 = jg * 8;
    const float* src = x + (size_t)(b * SEQ) * DMODEL + h * HDIM + d;
    float wmd = Wm[h * HDIM + d];
    half8 v;
    float fv[8];
#pragma unroll
    for (int jj = 0; jj < 8; ++jj) {
      float f = src[(size_t)(j0 + jj) * DMODEL];
      fv[jj] = f;
      v[jj] = (_Float16)f;
    }
    *(half8*)(xt + ((size_t)bh * HDIM + d) * SEQ + j0) = v;

    float msum = 0.f;
#pragma unroll
    for (int jj = 0; jj < 8; ++jj) {
      float s = fv[jj] * wmd;
#pragma unroll
      for (int off = 32; off; off >>= 1) s += __shfl_xor(s, off, 64);
      if (d == jj) msum = s;      // lane jj keeps row j0+jj's dot
    }
    if (d < 8) {
      float m = (msum > 20.f) ? msum : log1pf(expf(msum));
      masses[(size_t)bh * SEQ + j0 + d] = m;
    }
    return;
  }

  // ---- role B: invdist ----
  int ib = bid - 2048;
  int i0 = (ib >> 5) * 64, j0 = (ib & 31) * 64;

  int kk = (t & 15) * 4;
  int rr = t >> 4;
#pragma unroll
  for (int q = 0; q < 4; ++q) {
    int row = q * 16 + rr;
    float4 a = *(const float4*)(pos + (size_t)(i0 + row) * DPOS + kk);
    float4 b = *(const float4*)(pos + (size_t)(j0 + row) * DPOS + kk);
    Li[(kk + 0) * 68 + row] = a.x; Li[(kk + 1) * 68 + row] = a.y;
    Li[(kk + 2) * 68 + row] = a.z; Li[(kk + 3) * 68 + row] = a.w;
    Lj[(kk + 0) * 68 + row] = b.x; Lj[(kk + 1) * 68 + row] = b.y;
    Lj[(kk + 2) * 68 + row] = b.z; Lj[(kk + 3) * 68 + row] = b.w;
  }
  __syncthreads();

  int ti = (t >> 4) * 4;
  int tj = (t & 15) * 4;

  float acc[4][4];
#pragma unroll
  for (int a = 0; a < 4; ++a)
#pragma unroll
    for (int b = 0; b < 4; ++b) acc[a][b] = 0.f;

#pragma unroll 8
  for (int k = 0; k < 64; ++k) {
    float4 a = *(const float4*)(&Li[k * 68 + ti]);
    float4 b = *(const float4*)(&Lj[k * 68 + tj]);
    float av[4] = {a.x, a.y, a.z, a.w};
    float bv[4] = {b.x, b.y, b.z, b.w};
#pragma unroll
    for (int mi = 0; mi < 4; ++mi)
#pragma unroll
      for (int mj = 0; mj < 4; ++mj) {
        float d = av[mi] - bv[mj];
        acc[mi][mj] += d * d;
      }
  }

#pragma unroll
  for (int mi = 0; mi < 4; ++mi) {
    ushort4 o;
    unsigned short* op = (unsigned short*)&o;
#pragma unroll
    for (int mj = 0; mj < 4; ++mj) {
      float d2 = acc[mi][mj];
      float dn = sqrtf(d2 + EVENT_HORIZON);
      float w = d2 * (1.f + CURV * __cosf(dn));
      op[mj] = (unsigned short)bfbits(1.0f / fmaxf(w, EVENT_HORIZON));
    }
    *(ushort4*)(&invd[(size_t)(i0 + ti + mi) * SEQ + j0 + tj]) = o;
  }
}

// ---------------------------------------------------------------------------
// Kernel 3: fused gravitational attention, fp16 MFMA PV.
// r9 = r8 (block-level j-split: 2048 blocks, 64 i x 1024 j each, NaN guard)
// with the VGPR cap fixed. EMPIRICAL LAW (6 data points, r2-r8): the
// allocator cap = 256/min_waves_per_EU regardless of block size. r8's
// (256,8) -> cap 32 -> spill (50 MB scratch WRITE). (256,4) -> cap 64 >=
// ~50 demand -> no spill. The 2nd launch_bounds arg does NOT gate runtime
// occupancy -- that comes from resources (VGPR<=64 -> 8 waves/SIMD, LDS
// 16.5KB x 8 = 132KB, thread slots 2048/256 = 8 blocks/CU).
// ---------------------------------------------------------------------------
__global__ __launch_bounds__(256, 4) void attn_mfma_kernel(
    const _Float16* __restrict__ xt, const float* __restrict__ masses,
    const unsigned short* __restrict__ invd, const float* __restrict__ G,
    _Float16* __restrict__ A0, _Float16* __restrict__ A1,
    float* __restrict__ sums0, float* __restrict__ sums1) {
  __shared__ _Float16 Vs[2][64 * 64];   // [buf], 8 KB each, XOR-swizzled
  __shared__ float Ms[2][64];           // masses chunk broadcast

  constexpr float S2 = SHIFT * LOG2E;                 // 56.265
  constexpr float C2 = (MAX_FORCE - SHIFT) * LOG2E;   // 15.870

  int bid = blockIdx.x;
  // XCD-clustered bijective decode: x in [0,8) = XCD slot.
  int xs = bid & 7, y = bid >> 3;            // y in [0,256)
  int bh = xs * 4 + (y & 3);                 // 4 bh per XCD
  int rest = y >> 2;                         // [0,64)
  int jh = rest & 1;
  int iblk = rest >> 1;                      // [0,32)
  int h = bh & (NHEAD - 1), b = bh >> 4;
  int i0 = iblk * 64;
  int jbase = jh * 1024;
  int t = threadIdx.x, w = t >> 6, lane = t & 63;
  int l15 = lane & 15, quad = lane >> 4;
  int iw = i0 + w * 16;

  float gabs = fabsf(G[h]);
  const float* mrow = masses + (size_t)bh * SEQ;
  float cm = gabs * mrow[iw + l15] * LOG2E;           // row scalar, log2 domain
  const unsigned short* ivrow = invd + (size_t)(iw + l15) * SEQ + jbase;

  // staging role: thread t -> d-row t>>2, 16B-units {2*(t&3), 2*(t&3)+1}
  int srow = t >> 2, sunit = (t & 3) * 2;
  const _Float16* srcrow =
      xt + ((size_t)bh * HDIM + srow) * SEQ + jbase + sunit * 8;
  int swzoff0 = swz(srow, sunit) * 8;
  int swzoff1 = swz(srow, sunit + 1) * 8;

  half8 vone;
#pragma unroll
  for (int k = 0; k < 8; ++k) vone[k] = (_Float16)1.f;

  frag4f acc[4];
#pragma unroll
  for (int nt = 0; nt < 4; ++nt) acc[nt] = (frag4f)0.f;
  frag4f accs = (frag4f)0.f;          // partial row sums

  // ---- prologue: chunk 0 ----
  *(half8*)(&Vs[0][0] + swzoff0) = *(const half8*)(srcrow);
  *(half8*)(&Vs[0][0] + swzoff1) = *(const half8*)(srcrow + 8);
  if (t < 64) Ms[0][t] = mrow[jbase + t];
  frag8 iv_cur[2], iv_nxt[2];
  iv_cur[0] = *(const frag8*)(ivrow + quad * 8);
  iv_cur[1] = *(const frag8*)(ivrow + 32 + quad * 8);
  __syncthreads();

  for (int cc = 0; cc < 8; ++cc) {
#pragma unroll
    for (int u = 0; u < 2; ++u) {
      int c = cc * 2 + u;               // buf index u is compile-time
      // ---- issue prefetches for chunk c+1 (latency hidden by compute) ----
      half8 vpre0, vpre1;
      float mload = 0.f;
      if (c < 15) {
        int jn = (c + 1) * 64;
        vpre0 = *(const half8*)(srcrow + jn);
        vpre1 = *(const half8*)(srcrow + jn + 8);
        if (t < 64) mload = mrow[jbase + jn + t];
        iv_nxt[0] = *(const frag8*)(ivrow + jn + quad * 8);
        iv_nxt[1] = *(const frag8*)(ivrow + jn + 32 + quad * 8);
      }

      // ---- compute chunk c from buf[u] ----
      const _Float16* Vbase = &Vs[u][0];
      const float* Mbase = &Ms[u][0];

#pragma unroll
      for (int kh = 0; kh < 2; ++kh) {
        // masses broadcast from LDS (same addr across l15 -> bank broadcast)
        const float* mp = Mbase + kh * 32 + quad * 8;
        float4 mjl = *(const float4*)(mp);
        float4 mjh = *(const float4*)(mp + 4);
        float mjf[8] = {mjl.x, mjl.y, mjl.z, mjl.w,
                        mjh.x, mjh.y, mjh.z, mjh.w};
        uint4v uv = __builtin_bit_cast(uint4v, iv_cur[kh]);
        float e[8];
#pragma unroll
        for (int p = 0; p < 4; ++p) {
          float ivA = fbits(uv[p] << 16);          // even j: low bf16
          float ivB = fbits(uv[p] & 0xffff0000u);  // odd j: high bf16
          float fA = fmaf(cm * mjf[2 * p], ivA, -S2);
          float fB = fmaf(cm * mjf[2 * p + 1], ivB, -S2);
          e[2 * p] = exp2_fast(fminf(fA, C2));
          e[2 * p + 1] = exp2_fast(fminf(fB, C2));
        }
        A8u A;
#pragma unroll
        for (int p = 0; p < 4; ++p)
          A.h[p] = pkrtz(e[2 * p], e[2 * p + 1]);

        __builtin_amdgcn_s_setprio(1);
        accs = __builtin_amdgcn_mfma_f32_16x16x32_f16(A.v, vone, accs, 0, 0, 0);
#pragma unroll
        for (int nt = 0; nt < 4; ++nt) {
          half8 Bf = *(const half8*)(Vbase + swz(nt * 16 + l15, kh * 4 + quad) * 8);
          acc[nt] = __builtin_amdgcn_mfma_f32_16x16x32_f16(A.v, Bf, acc[nt], 0, 0, 0);
        }
        __builtin_amdgcn_s_setprio(0);
      }

      // ---- rotate prefetches in; write V/M prefetch to other buffer ----
      if (c < 15) {
        _Float16* Vn = &Vs[u ^ 1][0];
        *(half8*)(Vn + swzoff0) = vpre0;
        *(half8*)(Vn + swzoff1) = vpre1;
        if (t < 64) Ms[u ^ 1][t] = mload;
        iv_cur[0] = iv_nxt[0]; iv_cur[1] = iv_nxt[1];
      }
      __syncthreads();
    }
  }

  // ---- self-normalize partial + store fp16 tile and partial row sums.
  // accs==0 (all-underflow half) -> partial is exactly 0; store s=0 so the
  // combine weight is 0 for this half. ----
  _Float16* Aout = jh ? A1 : A0;
  float* sout = jh ? sums1 : sums0;
#pragma unroll
  for (int reg = 0; reg < 4; ++reg) {
    int r = quad * 4 + reg;            // C/D row within 16x16 tile
    size_t m = (size_t)(b * SEQ + iw + r);
    float s = (accs[reg] > 0.f) ? (1.f / accs[reg]) : 0.f;
#pragma unroll
    for (int nt = 0; nt < 4; ++nt) {
      Aout[m * DMODEL + h * HDIM + nt * 16 + l15] =
          (_Float16)(acc[nt][reg] * s);
    }
    if (l15 == 0) sout[m * NHEAD + h] = accs[reg];
  }
}

// ---------------------------------------------------------------------------
// Kernel 4: out = combine(A0,A1) @ Wout^T via fp16 MFMA. A-staging combines
// the two j-half partials: A = w0*A0 + w1*A1, w0 = s0/(s0+s1), via packed
// fp16 fma (BK=64 == head dim -> one weight scalar per (row, kc)). Wout
// f32->fp16 on the fly in B-staging. 128x64 tile, double-buffered swizzled
// LDS. grid (16,32) = 512 blocks.
// ---------------------------------------------------------------------------
__global__ __launch_bounds__(256) void out_gemm_mfma(
    const _Float16* __restrict__ A0, const _Float16* __restrict__ A1,
    const float* __restrict__ sums0, const float* __restrict__ sums1,
    const float* __restrict__ Wout, float* __restrict__ C) {
  __shared__ _Float16 As[2][128 * 64];   // 16 KB each
  __shared__ _Float16 Bs[2][64 * 64];    // 8 KB each

  int t = threadIdx.x, w = t >> 6, lane = t & 63;
  int l15 = lane & 15, quad = lane >> 4;
  int m0 = blockIdx.y * 128, n0 = blockIdx.x * 64;
  int mh = (w & 1) * 64, nh = (w >> 1) * 32;

  int ar = t >> 1;  int aku = (t & 1) * 4;
  int br = t >> 2;  int bku = (t & 3) * 2;
  const _Float16* a0base = A0 + (size_t)(m0 + ar) * DMODEL + aku * 8;
  const _Float16* a1base = A1 + (size_t)(m0 + ar) * DMODEL + aku * 8;
  const float* s0p = sums0 + (size_t)(m0 + ar) * NHEAD;
  const float* s1p = sums1 + (size_t)(m0 + ar) * NHEAD;
  const float*    wbase = Wout + (size_t)(n0 + br) * DMODEL + bku * 8;

  frag4f acc[4][2];
#pragma unroll
  for (int mt = 0; mt < 4; ++mt)
#pragma unroll
    for (int nt = 0; nt < 2; ++nt) acc[mt][nt] = (frag4f)0.f;

  A8u a0q[4], a1q[4];
  half8 b0, b1;
  float s0, s1;

  // combine helper runs at staging-write time
  auto stage = [&](int buf) {
    float w0f = s0 / (s0 + s1);
    _Float16 w0 = (_Float16)w0f;
    _Float16 w1 = (_Float16)(1.f - w0f);
    half2t w0h = {w0, w0}, w1h = {w1, w1};
    _Float16* aw = As[buf]; _Float16* bw = Bs[buf];
#pragma unroll
    for (int q = 0; q < 4; ++q) {
      A8u o;
#pragma unroll
      for (int p = 0; p < 4; ++p)
        o.h[p] = a0q[q].h[p] * w0h + a1q[q].h[p] * w1h;   // v_pk_fma_f16
      *(half8*)(aw + swz(ar, aku + q) * 8) = o.v;
    }
    *(half8*)(bw + swz(br, bku + 0) * 8) = b0;
    *(half8*)(bw + swz(br, bku + 1) * 8) = b1;
  };
  auto loadk = [&](int kc) {
    const _Float16* ap0 = a0base + kc * 64;
    const _Float16* ap1 = a1base + kc * 64;
#pragma unroll
    for (int q = 0; q < 4; ++q) {
      a0q[q].v = *(const half8*)(ap0 + q * 8);
      a1q[q].v = *(const half8*)(ap1 + q * 8);
    }
    s0 = s0p[kc]; s1 = s1p[kc];
    const float* wp = wbase + kc * 64;
    float4 w0 = *(const float4*)(wp);      float4 w1 = *(const float4*)(wp + 4);
    float4 w2 = *(const float4*)(wp + 8);  float4 w3 = *(const float4*)(wp + 12);
    b0[0] = (_Float16)w0.x; b0[1] = (_Float16)w0.y; b0[2] = (_Float16)w0.z; b0[3] = (_Float16)w0.w;
    b0[4] = (_Float16)w1.x; b0[5] = (_Float16)w1.y; b0[6] = (_Float16)w1.z; b0[7] = (_Float16)w1.w;
    b1[0] = (_Float16)w2.x; b1[1] = (_Float16)w2.y; b1[2] = (_Float16)w2.z; b1[3] = (_Float16)w2.w;
    b1[4] = (_Float16)w3.x; b1[5] = (_Float16)w3.y; b1[6] = (_Float16)w3.z; b1[7] = (_Float16)w3.w;
  };

  loadk(0);
  stage(0);
  __syncthreads();

  for (int kk = 0; kk < 8; ++kk) {
#pragma unroll
    for (int u = 0; u < 2; ++u) {
      int kc = kk * 2 + u;              // buf index u is compile-time
      if (kc < 15) loadk(kc + 1);

      const _Float16* ac = As[u];
      const _Float16* bc = Bs[u];
#pragma unroll
      for (int kh = 0; kh < 2; ++kh) {
        half8 Af[4], Bf[2];
#pragma unroll
        for (int mt = 0; mt < 4; ++mt)
          Af[mt] = *(const half8*)(ac + swz(mh + mt * 16 + l15, kh * 4 + quad) * 8);
#pragma unroll
        for (int nt = 0; nt < 2; ++nt)
          Bf[nt] = *(const half8*)(bc + swz(nh + nt * 16 + l15, kh * 4 + quad) * 8);
        __builtin_amdgcn_s_setprio(1);
#pragma unroll
        for (int mt = 0; mt < 4; ++mt)
#pragma unroll
          for (int nt = 0; nt < 2; ++nt)
            acc[mt][nt] = __builtin_amdgcn_mfma_f32_16x16x32_f16(Af[mt], Bf[nt], acc[mt][nt], 0, 0, 0);
        __builtin_amdgcn_s_setprio(0);
      }

      if (kc < 15) stage(u ^ 1);
      __syncthreads();
    }
  }

#pragma unroll
  for (int mt = 0; mt < 4; ++mt)
#pragma unroll
    for (int nt = 0; nt < 2; ++nt)
#pragma unroll
      for (int reg = 0; reg < 4; ++reg) {
        int m = m0 + mh + mt * 16 + quad * 4 + reg;
        int n = n0 + nh + nt * 16 + l15;
        C[(size_t)m * DMODEL + n] = acc[mt][nt][reg];
      }
}

// ---------------------------------------------------------------------------
extern "C" void kernel_launch(void* const* d_in, const int* in_sizes, int n_in,
                              void* d_out, int out_size, void* d_ws, size_t ws_size,
                              hipStream_t stream) {
  const float* x    = (const float*)d_in[0];
  const float* pos  = (const float*)d_in[1];
  const float* Wm   = (const float*)d_in[2];
  const float* G    = (const float*)d_in[3];
  const float* Wout = (const float*)d_in[4];
  float* out = (float*)d_out;

  char* wsb = (char*)d_ws;
  float* masses = (float*)wsb;                                      // 256 KB
  unsigned short* invd = (unsigned short*)(wsb + (1 << 18));        // 8 MB
  _Float16* A0 = (_Float16*)(wsb + (1 << 18) + (8 << 20));          // 8 MB
  _Float16* A1 = (_Float16*)(wsb + (1 << 18) + (16 << 20));         // 8 MB
  _Float16* xt = (_Float16*)(wsb + (1 << 18) + (24 << 20));         // 8 MB
  float* sums0 = (float*)(wsb + (1 << 18) + (32 << 20));            // 256 KB
  float* sums1 = (float*)(wsb + (1 << 18) + (32 << 20) + (1 << 18));// 256 KB

  prep_and_dist<<<dim3(3072), 256, 0, stream>>>(x, Wm, pos, xt, masses, invd);
  attn_mfma_kernel<<<dim3(2048), 256, 0, stream>>>(
      xt, masses, invd, G, A0, A1, sums0, sums1);
  out_gemm_mfma<<<dim3(DMODEL / 64, (BATCH * SEQ) / 128), 256, 0, stream>>>(
      A0, A1, sums0, sums1, Wout, out);
}

// Round 10
// 155.089 us; speedup vs baseline: 1.2576x; 1.1040x over previous
//
#include <hip/hip_runtime.h>
#include <hip/hip_bf16.h>

#define SEQ 2048
#define DMODEL 1024
#define NHEAD 16
#define HDIM 64
#define DPOS 64
#define BATCH 2

constexpr float EVENT_HORIZON = 1e-6f;
constexpr float MAX_FORCE = 50.0f;
constexpr float CURV = 0.15f;
constexpr float LOG2E = 1.44269504f;
// P = exp2(min(f,50)*log2e - S2), S2 = 39*log2e: e <= 2^15.87 = 59847 (fp16-safe),
// ratio-invariant under softmax normalization.
constexpr float SHIFT = 39.0f;

typedef __attribute__((ext_vector_type(8))) short frag8;        // 8 bf16/ushort
typedef __attribute__((ext_vector_type(4))) unsigned int uint4v;
typedef __attribute__((ext_vector_type(8))) _Float16 half8;     // 8 fp16
typedef __attribute__((ext_vector_type(2))) _Float16 half2t;    // 2 fp16
typedef __attribute__((ext_vector_type(4))) float frag4f;       // 4 fp32 (C/D)

union A8u { half8 v; half2t h[4]; };

__device__ inline short bfbits(float f) {
  __hip_bfloat16 h = __float2bfloat16(f);
  return *reinterpret_cast<short*>(&h);
}
__device__ inline float fbits(unsigned u) {
  union { unsigned u; float f; } c; c.u = u; return c.f;
}
__device__ inline half2t pkrtz(float a, float b) {
  return __builtin_bit_cast(half2t, __builtin_amdgcn_cvt_pkrtz(a, b));
}
// native 2^x, single v_exp_f32 (no hidden *log2e mul like __expf)
__device__ inline float exp2_fast(float x) {
  float r;
  asm("v_exp_f32 %0, %1" : "=v"(r) : "v"(x));
  return r;
}
// XOR swizzle in 16B units: row = 8 units (128B); b128 frag reads (fixed unit,
// 16 consecutive rows) and staging writes both cover banks <=2-way (free).
__device__ inline int swz(int row, int u) { return row * 8 + (u ^ (row & 7)); }

// ---------------------------------------------------------------------------
// Fused prep (role A, 2048 blocks) + invdist (role B, 1024 blocks).
// Role A: transpose x -> xt[bh][d][j] fp16 AND masses = softplus(x . Wm).
// Role B: LDS-tiled pairwise distance -> invd bf16. r10: SYMMETRY — blocks
// with i0 > j0 exit immediately (halves compute); i0 <= j0 blocks write the
// tile AND its transpose (thread already holds the 4x4; diagonal tiles
// write identical values twice, benign since dist(a,b)==dist(b,a) exactly).
// ---------------------------------------------------------------------------
__global__ __launch_bounds__(256) void prep_and_dist(
    const float* __restrict__ x, const float* __restrict__ Wm,
    const float* __restrict__ pos,
    _Float16* __restrict__ xt, float* __restrict__ masses,
    unsigned short* __restrict__ invd) {
  __shared__ float Li[64 * 68];
  __shared__ float Lj[64 * 68];
  int bid = blockIdx.x;
  int t = threadIdx.x;

  if (bid < 2048) {
    // ---- role A: prep_xt_masses ----
    int bh = bid & 31;
    int h = bh & 15, b = bh >> 4;
    int d = t & 63;
    int jg = (t >> 6) + ((bid >> 5) << 2);   // j-group of 8, 0..255
    int j0 = jg * 8;
    const float* src = x + (size_t)(b * SEQ) * DMODEL + h * HDIM + d;
    float wmd = Wm[h * HDIM + d];
    half8 v;
    float fv[8];
#pragma unroll
    for (int jj = 0; jj < 8; ++jj) {
      float f = src[(size_t)(j0 + jj) * DMODEL];
      fv[jj] = f;
      v[jj] = (_Float16)f;
    }
    *(half8*)(xt + ((size_t)bh * HDIM + d) * SEQ + j0) = v;

    float msum = 0.f;
#pragma unroll
    for (int jj = 0; jj < 8; ++jj) {
      float s = fv[jj] * wmd;
#pragma unroll
      for (int off = 32; off; off >>= 1) s += __shfl_xor(s, off, 64);
      if (d == jj) msum = s;      // lane jj keeps row j0+jj's dot
    }
    if (d < 8) {
      float m = (msum > 20.f) ? msum : log1pf(expf(msum));
      masses[(size_t)bh * SEQ + j0 + d] = m;
    }
    return;
  }

  // ---- role B: invdist (upper triangle only, dual write) ----
  int ib = bid - 2048;
  int i0 = (ib >> 5) * 64, j0 = (ib & 31) * 64;
  if (i0 > j0) return;                       // symmetry: skip lower triangle

  int kk = (t & 15) * 4;
  int rr = t >> 4;
#pragma unroll
  for (int q = 0; q < 4; ++q) {
    int row = q * 16 + rr;
    float4 a = *(const float4*)(pos + (size_t)(i0 + row) * DPOS + kk);
    float4 b = *(const float4*)(pos + (size_t)(j0 + row) * DPOS + kk);
    Li[(kk + 0) * 68 + row] = a.x; Li[(kk + 1) * 68 + row] = a.y;
    Li[(kk + 2) * 68 + row] = a.z; Li[(kk + 3) * 68 + row] = a.w;
    Lj[(kk + 0) * 68 + row] = b.x; Lj[(kk + 1) * 68 + row] = b.y;
    Lj[(kk + 2) * 68 + row] = b.z; Lj[(kk + 3) * 68 + row] = b.w;
  }
  __syncthreads();

  int ti = (t >> 4) * 4;
  int tj = (t & 15) * 4;

  float acc[4][4];
#pragma unroll
  for (int a = 0; a < 4; ++a)
#pragma unroll
    for (int b = 0; b < 4; ++b) acc[a][b] = 0.f;

#pragma unroll 8
  for (int k = 0; k < 64; ++k) {
    float4 a = *(const float4*)(&Li[k * 68 + ti]);
    float4 b = *(const float4*)(&Lj[k * 68 + tj]);
    float av[4] = {a.x, a.y, a.z, a.w};
    float bv[4] = {b.x, b.y, b.z, b.w};
#pragma unroll
    for (int mi = 0; mi < 4; ++mi)
#pragma unroll
      for (int mj = 0; mj < 4; ++mj) {
        float d = av[mi] - bv[mj];
        acc[mi][mj] += d * d;
      }
  }

  unsigned short op[4][4];
#pragma unroll
  for (int mi = 0; mi < 4; ++mi) {
#pragma unroll
    for (int mj = 0; mj < 4; ++mj) {
      float d2 = acc[mi][mj];
      float dn = sqrtf(d2 + EVENT_HORIZON);
      float wv = d2 * (1.f + CURV * __cosf(dn));
      op[mi][mj] = (unsigned short)bfbits(1.0f / fmaxf(wv, EVENT_HORIZON));
    }
    ushort4 o = {op[mi][0], op[mi][1], op[mi][2], op[mi][3]};
    *(ushort4*)(&invd[(size_t)(i0 + ti + mi) * SEQ + j0 + tj]) = o;
  }
  // transposed tile write (thread already holds the 4x4)
#pragma unroll
  for (int mj = 0; mj < 4; ++mj) {
    ushort4 o = {op[0][mj], op[1][mj], op[2][mj], op[3][mj]};
    *(ushort4*)(&invd[(size_t)(j0 + tj + mj) * SEQ + i0 + ti]) = o;
  }
}

// ---------------------------------------------------------------------------
// Kernel 3: fused gravitational attention, fp16 MFMA PV. r10 = r6 verbatim
// (best measured attn: 49.8 us). 256 thr = 4 waves x 16 i-rows, grid 1024
// XCD-clustered, LDS masses broadcast, chunk loop unrolled x2,
// launch_bounds(256,4) -> VGPR cap 64 (cap law: 256/min_waves_per_EU).
// ---------------------------------------------------------------------------
__global__ __launch_bounds__(256, 4) void attn_mfma_kernel(
    const _Float16* __restrict__ xt, const float* __restrict__ masses,
    const unsigned short* __restrict__ invd, const float* __restrict__ G,
    _Float16* __restrict__ attnout) {
  __shared__ _Float16 Vs[2][64 * 64];   // [buf], 8 KB each, XOR-swizzled
  __shared__ float Ms[2][64];           // masses chunk broadcast

  constexpr float S2 = SHIFT * LOG2E;                 // 56.265
  constexpr float C2 = (MAX_FORCE - SHIFT) * LOG2E;   // 15.870

  int bid = blockIdx.x;
  int bh = (bid & 7) * 4 + ((bid >> 3) & 3);   // XCD-clustered: 4 bh per XCD
  int iblk = bid >> 5;
  int h = bh & (NHEAD - 1), b = bh >> 4;
  int i0 = iblk * 64;
  int t = threadIdx.x, w = t >> 6, lane = t & 63;
  int l15 = lane & 15, quad = lane >> 4;
  int iw = i0 + w * 16;

  float gabs = fabsf(G[h]);
  const float* mrow = masses + (size_t)bh * SEQ;
  float cm = gabs * mrow[iw + l15] * LOG2E;           // row scalar, log2 domain
  const unsigned short* ivrow = invd + (size_t)(iw + l15) * SEQ;

  // staging role: thread t -> d-row t>>2, 16B-units {2*(t&3), 2*(t&3)+1}
  int srow = t >> 2, sunit = (t & 3) * 2;
  const _Float16* srcrow =
      xt + ((size_t)bh * HDIM + srow) * SEQ + sunit * 8;
  int swzoff0 = swz(srow, sunit) * 8;
  int swzoff1 = swz(srow, sunit + 1) * 8;

  half8 vone;
#pragma unroll
  for (int k = 0; k < 8; ++k) vone[k] = (_Float16)1.f;

  frag4f acc[4];
#pragma unroll
  for (int nt = 0; nt < 4; ++nt) acc[nt] = (frag4f)0.f;
  frag4f accs = (frag4f)0.f;          // row sums (every column identical)

  // ---- prologue: chunk 0 ----
  *(half8*)(&Vs[0][0] + swzoff0) = *(const half8*)(srcrow);
  *(half8*)(&Vs[0][0] + swzoff1) = *(const half8*)(srcrow + 8);
  if (t < 64) Ms[0][t] = mrow[t];
  frag8 iv_cur[2], iv_nxt[2];
  iv_cur[0] = *(const frag8*)(ivrow + quad * 8);
  iv_cur[1] = *(const frag8*)(ivrow + 32 + quad * 8);
  __syncthreads();

  for (int cc = 0; cc < 16; ++cc) {
#pragma unroll
    for (int u = 0; u < 2; ++u) {
      int c = cc * 2 + u;               // buf index u is compile-time
      // ---- issue prefetches for chunk c+1 (latency hidden by compute) ----
      half8 vpre0, vpre1;
      float mload = 0.f;
      if (c < 31) {
        int jn = (c + 1) * 64;
        vpre0 = *(const half8*)(srcrow + jn);
        vpre1 = *(const half8*)(srcrow + jn + 8);
        if (t < 64) mload = mrow[jn + t];
        iv_nxt[0] = *(const frag8*)(ivrow + jn + quad * 8);
        iv_nxt[1] = *(const frag8*)(ivrow + jn + 32 + quad * 8);
      }

      // ---- compute chunk c from buf[u] ----
      const _Float16* Vbase = &Vs[u][0];
      const float* Mbase = &Ms[u][0];

#pragma unroll
      for (int kh = 0; kh < 2; ++kh) {
        // masses broadcast from LDS (same addr across l15 -> bank broadcast)
        const float* mp = Mbase + kh * 32 + quad * 8;
        float4 mjl = *(const float4*)(mp);
        float4 mjh = *(const float4*)(mp + 4);
        float mjf[8] = {mjl.x, mjl.y, mjl.z, mjl.w,
                        mjh.x, mjh.y, mjh.z, mjh.w};
        uint4v uv = __builtin_bit_cast(uint4v, iv_cur[kh]);
        float e[8];
#pragma unroll
        for (int p = 0; p < 4; ++p) {
          float ivA = fbits(uv[p] << 16);          // even j: low bf16
          float ivB = fbits(uv[p] & 0xffff0000u);  // odd j: high bf16
          float fA = fmaf(cm * mjf[2 * p], ivA, -S2);
          float fB = fmaf(cm * mjf[2 * p + 1], ivB, -S2);
          e[2 * p] = exp2_fast(fminf(fA, C2));
          e[2 * p + 1] = exp2_fast(fminf(fB, C2));
        }
        A8u A;
#pragma unroll
        for (int p = 0; p < 4; ++p)
          A.h[p] = pkrtz(e[2 * p], e[2 * p + 1]);

        __builtin_amdgcn_s_setprio(1);
        accs = __builtin_amdgcn_mfma_f32_16x16x32_f16(A.v, vone, accs, 0, 0, 0);
#pragma unroll
        for (int nt = 0; nt < 4; ++nt) {
          half8 Bf = *(const half8*)(Vbase + swz(nt * 16 + l15, kh * 4 + quad) * 8);
          acc[nt] = __builtin_amdgcn_mfma_f32_16x16x32_f16(A.v, Bf, acc[nt], 0, 0, 0);
        }
        __builtin_amdgcn_s_setprio(0);
      }

      // ---- rotate prefetches in; write V/M prefetch to other buffer ----
      if (c < 31) {
        _Float16* Vn = &Vs[u ^ 1][0];
        *(half8*)(Vn + swzoff0) = vpre0;
        *(half8*)(Vn + swzoff1) = vpre1;
        if (t < 64) Ms[u ^ 1][t] = mload;
        iv_cur[0] = iv_nxt[0]; iv_cur[1] = iv_nxt[1];
      }
      __syncthreads();
    }
  }

  // ---- normalize + store (accs[reg] already holds row r = quad*4+reg) ----
#pragma unroll
  for (int reg = 0; reg < 4; ++reg) {
    int r = quad * 4 + reg;            // C/D row within 16x16 tile
    float s = 1.f / accs[reg];
#pragma unroll
    for (int nt = 0; nt < 4; ++nt) {
      attnout[(size_t)(b * SEQ + iw + r) * DMODEL + h * HDIM + nt * 16 + l15] =
          (_Float16)(acc[nt][reg] * s);
    }
  }
}

// ---------------------------------------------------------------------------
// Kernel 4: out = attnout @ Wout^T via fp16 MFMA, Wout f32->fp16 on the fly.
// r10: 512 thr = 8 waves on the 128(M)x64(N) tile; each wave 32m x 32n
// (2x2 frags, 16 acc regs). LDS 48 KB -> 3 blocks/CU -> 24 waves/CU (was
// 2 blocks/CU, 8 waves/CU with 256 thr). launch_bounds(512,4) -> VGPR cap
// 64 >= ~55 demand. Double-buffered swizzled LDS, unroll-2 K loop.
// ---------------------------------------------------------------------------
__global__ __launch_bounds__(512, 4) void out_gemm_mfma(
    const _Float16* __restrict__ Ag, const float* __restrict__ Wout,
    float* __restrict__ C) {
  __shared__ _Float16 As[2][128 * 64];   // 16 KB each
  __shared__ _Float16 Bs[2][64 * 64];    // 8 KB each

  int t = threadIdx.x, w = t >> 6, lane = t & 63;
  int l15 = lane & 15, quad = lane >> 4;
  int m0 = blockIdx.y * 128, n0 = blockIdx.x * 64;
  int mh = (w >> 1) * 32, nh = (w & 1) * 32;

  int ar = t >> 2;  int au = (t & 3) * 2;   // A: row 0..127, units {au,au+1}
  int br = t >> 3;  int bu = t & 7;         // B: row 0..63, unit bu
  const _Float16* abase = Ag + (size_t)(m0 + ar) * DMODEL + au * 8;
  const float*    wbase = Wout + (size_t)(n0 + br) * DMODEL + bu * 8;

  frag4f acc[2][2];
#pragma unroll
  for (int mt = 0; mt < 2; ++mt)
#pragma unroll
    for (int nt = 0; nt < 2; ++nt) acc[mt][nt] = (frag4f)0.f;

  half8 a0, a1, b0;
  auto loadk = [&](int kc) {
    const _Float16* ap = abase + kc * 64;
    a0 = *(const half8*)(ap);
    a1 = *(const half8*)(ap + 8);
    const float* wp = wbase + kc * 64;
    float4 w0 = *(const float4*)(wp);
    float4 w1 = *(const float4*)(wp + 4);
    b0[0] = (_Float16)w0.x; b0[1] = (_Float16)w0.y;
    b0[2] = (_Float16)w0.z; b0[3] = (_Float16)w0.w;
    b0[4] = (_Float16)w1.x; b0[5] = (_Float16)w1.y;
    b0[6] = (_Float16)w1.z; b0[7] = (_Float16)w1.w;
  };
  auto stage = [&](int buf) {
    _Float16* aw = As[buf]; _Float16* bw = Bs[buf];
    *(half8*)(aw + swz(ar, au + 0) * 8) = a0;
    *(half8*)(aw + swz(ar, au + 1) * 8) = a1;
    *(half8*)(bw + swz(br, bu) * 8) = b0;
  };

  loadk(0);
  stage(0);
  __syncthreads();

  for (int kk = 0; kk < 8; ++kk) {
#pragma unroll
    for (int u = 0; u < 2; ++u) {
      int kc = kk * 2 + u;              // buf index u is compile-time
      if (kc < 15) loadk(kc + 1);

      const _Float16* ac = As[u];
      const _Float16* bc = Bs[u];
#pragma unroll
      for (int kh = 0; kh < 2; ++kh) {
        half8 Af[2], Bf[2];
#pragma unroll
        for (int mt = 0; mt < 2; ++mt)
          Af[mt] = *(const half8*)(ac + swz(mh + mt * 16 + l15, kh * 4 + quad) * 8);
#pragma unroll
        for (int nt = 0; nt < 2; ++nt)
          Bf[nt] = *(const half8*)(bc + swz(nh + nt * 16 + l15, kh * 4 + quad) * 8);
        __builtin_amdgcn_s_setprio(1);
#pragma unroll
        for (int mt = 0; mt < 2; ++mt)
#pragma unroll
          for (int nt = 0; nt < 2; ++nt)
            acc[mt][nt] = __builtin_amdgcn_mfma_f32_16x16x32_f16(Af[mt], Bf[nt], acc[mt][nt], 0, 0, 0);
        __builtin_amdgcn_s_setprio(0);
      }

      if (kc < 15) stage(u ^ 1);
      __syncthreads();
    }
  }

#pragma unroll
  for (int mt = 0; mt < 2; ++mt)
#pragma unroll
    for (int nt = 0; nt < 2; ++nt)
#pragma unroll
      for (int reg = 0; reg < 4; ++reg) {
        int m = m0 + mh + mt * 16 + quad * 4 + reg;
        int n = n0 + nh + nt * 16 + l15;
        C[(size_t)m * DMODEL + n] = acc[mt][nt][reg];
      }
}

// ---------------------------------------------------------------------------
extern "C" void kernel_launch(void* const* d_in, const int* in_sizes, int n_in,
                              void* d_out, int out_size, void* d_ws, size_t ws_size,
                              hipStream_t stream) {
  const float* x    = (const float*)d_in[0];
  const float* pos  = (const float*)d_in[1];
  const float* Wm   = (const float*)d_in[2];
  const float* G    = (const float*)d_in[3];
  const float* Wout = (const float*)d_in[4];
  float* out = (float*)d_out;

  char* wsb = (char*)d_ws;
  float* masses = (float*)wsb;                                    // 256 KB
  unsigned short* invd = (unsigned short*)(wsb + (1 << 18));      // 8 MB
  _Float16* attnout = (_Float16*)(wsb + (1 << 18) + (8 << 20));   // 8 MB
  _Float16* xt      = (_Float16*)(wsb + (1 << 18) + (16 << 20));  // 8 MB

  prep_and_dist<<<dim3(3072), 256, 0, stream>>>(x, Wm, pos, xt, masses, invd);
  attn_mfma_kernel<<<dim3(1024), 256, 0, stream>>>(
      xt, masses, invd, G, attnout);
  out_gemm_mfma<<<dim3(DMODEL / 64, (BATCH * SEQ) / 128), 512, 0, stream>>>(
      attnout, Wout, out);
}